// Round 19
// baseline (201.484 us; speedup 1.0000x reference)
//
#include <hip/hip_runtime.h>

// out[b,c,y,x] = sum_{kdy,kdx in [0,9)} corr[b, kdy*9+kdx, y+4-kdy, x+4-kdx] * feat[b,c, y+4-kdy, x+4-kdx]
// R19: rolling-row MFMA. Prepasses (R18-verified): featb = bf16(feat);
//   mband[(b*96+sy)*9+kdy][x][o] = bf16(corr[b, kdy*9+(x+8-(kb+o)), sy, kb+o-4]), 0 OOB,
//   kb(x) = x<80 ? x&~15 : 72.
// Main: block = (b, 32-ch group, 8 consecutive y); wave w owns y = y0+w.
//   Iterate sy = y0-4 .. y0+11 (16 steps): stage A row ONCE (dbuf, 1 barrier/step);
//   wave w active iff kdy = w+8-s in [0,9) and sy valid; B-fragments read DIRECTLY from
//   mband (global, coalesced 1KB segments, L2-hot via 8x cg reuse).

#define RR 4
#define DD 9
#define D2 81
#define Bn 16
#define Cn 256
#define Hn 96
#define Wn 96
#define HWn (Hn*Wn)
#define MW  32

typedef __attribute__((ext_vector_type(8))) short bf16x8;
typedef __attribute__((ext_vector_type(4))) float f32x4;

__device__ __forceinline__ uint cvt_pk(float lo, float hi) {
    uint r;
    asm("v_cvt_pk_bf16_f32 %0, %1, %2" : "=v"(r) : "v"(lo), "v"(hi));
    return r;
}
__device__ __forceinline__ ushort f2bf(float f) {
    uint u = __float_as_uint(f);
    return (ushort)((u + 0x7FFFu + ((u >> 16) & 1u)) >> 16);
}

// ---- fused prepass (R18-verified): blocks [0,1536) build mband, rest convert feat ----
#define PREP_MB (Bn*Hn)          // 1536
#define PREP_FT 2560
__global__ __launch_bounds__(384)
void prep_all_kernel(const float* __restrict__ feat, const float* __restrict__ corr,
                     ushort* __restrict__ featb, ushort* __restrict__ mband)
{
    if (blockIdx.x < PREP_MB) {
        const int s  = blockIdx.x;               // b*Hn + sy
        const int sy = s % Hn, b = s / Hn;
        const float* cb = corr + (size_t)b * D2 * HWn + (size_t)sy * Wn;
        const int t   = threadIdx.x;             // 384 = 96 x * 4 octets
        const int x   = t >> 2, oct = t & 3;
        const int kb  = (x >= 80) ? 72 : (x & ~15);
        ushort* mbase = mband + ((size_t)s * DD) * (Wn * MW) + x * MW + oct * 8;
        #pragma unroll 1
        for (int kdy = 0; kdy < DD; ++kdy) {
            ushort v[8];
            #pragma unroll
            for (int i = 0; i < 8; ++i) {
                int o   = oct * 8 + i;
                int sxp = kb + o;
                int kdx = x + 2 * RR - sxp;
                float f = 0.f;
                if (kdx >= 0 && kdx < DD && sxp >= RR && sxp < Wn + RR)
                    f = cb[(size_t)(kdy * DD + kdx) * HWn + (sxp - RR)];
                v[i] = f2bf(f);
            }
            *reinterpret_cast<uint4*>(mbase + (size_t)kdy * (Wn * MW)) =
                make_uint4((uint)v[0] | ((uint)v[1] << 16), (uint)v[2] | ((uint)v[3] << 16),
                           (uint)v[4] | ((uint)v[5] << 16), (uint)v[6] | ((uint)v[7] << 16));
        }
    } else {
        const int n8 = Bn * Cn * HWn / 8;
        const float4* src = reinterpret_cast<const float4*>(feat);
        uint4* dst = reinterpret_cast<uint4*>(featb);
        for (int i = (blockIdx.x - PREP_MB) * 384 + threadIdx.x; i < n8; i += PREP_FT * 384) {
            float4 a = src[2 * i], c = src[2 * i + 1];
            dst[i] = make_uint4(cvt_pk(a.x, a.y), cvt_pk(a.z, a.w), cvt_pk(c.x, c.y), cvt_pk(c.z, c.w));
        }
    }
}

// ---- main: rolling-row, 8 waves = 8 y, A dbuf in LDS, M direct from mband ----
__global__ __launch_bounds__(512, 4)
void corrT19_kernel(const ushort* __restrict__ featb, const ushort* __restrict__ mband,
                    float* __restrict__ out)
{
    __shared__ ushort A_sh[2][32][104];   // 13312 B

    // grid 1536 = 8 XCD chunks * 192; within chunk: cg innermost (8 cg share mband slices)
    int bid = blockIdx.x;
    int L   = (bid & 7) * 192 + (bid >> 3);
    int cg  = L & 7;
    int yt  = (L >> 3) % 12;
    int b   = L / 96;
    const int y0 = yt * 8, c0 = cg * 32;

    const int tid  = threadIdx.x;
    const int lane = tid & 63;
    const int wid  = tid >> 6;            // wave w -> y0+w
    const int mrow = lane & 15;
    const int kq   = lane >> 4;
    const int kgrp = kq << 3;

    // zero pads (cols 0-3 / 100-103) of both buffers once
    if (tid < 64) {
        int bf = tid >> 5, row = tid & 31;
        *reinterpret_cast<uint2*>(&A_sh[bf][row][0])   = make_uint2(0u, 0u);
        *reinterpret_cast<uint2*>(&A_sh[bf][row][100]) = make_uint2(0u, 0u);
    }

    // stager mapping: 192 threads, 6 per row, 16 ushorts (2 uint4) each
    const bool stager = (tid < 192);
    const int  srow   = stager ? (tid / 6) : 0;
    const int  sseg   = tid % 6;
    const ushort* fbase = featb + (((size_t)b * Cn + c0 + srow) * Hn) * (size_t)Wn + sseg * 16;

    // prologue: stage sy = y0-4 into buf 0
    {
        const int sy = y0 - 4;
        if (stager && sy >= 0) {
            const uint4* p = reinterpret_cast<const uint4*>(fbase + (size_t)sy * Wn);
            uint4 v0 = p[0], v1 = p[1];
            uint2* d = reinterpret_cast<uint2*>(&A_sh[0][srow][4 + sseg * 16]);
            d[0] = make_uint2(v0.x, v0.y); d[1] = make_uint2(v0.z, v0.w);
            d[2] = make_uint2(v1.x, v1.y); d[3] = make_uint2(v1.z, v1.w);
        }
    }
    __syncthreads();

    f32x4 acc[2][6];
    #pragma unroll
    for (int ct = 0; ct < 2; ++ct)
        #pragma unroll
        for (int t6 = 0; t6 < 6; ++t6)
            acc[ct][t6] = (f32x4){0.f, 0.f, 0.f, 0.f};

    #pragma unroll 1
    for (int s = 0; s < 16; ++s) {
        const int pb = s & 1;

        // T14 issue-early: next A row loads held in regs across the MFMA phase
        const int syn = y0 - 4 + s + 1;
        uint4 v0, v1;
        const bool doSt = stager && (s < 15) && (syn >= 0) && (syn < Hn);
        if (doSt) {
            const uint4* p = reinterpret_cast<const uint4*>(fbase + (size_t)syn * Wn);
            v0 = p[0]; v1 = p[1];
        }

        // compute: wave w consumes A[sy] with its own kdy slice of mband
        const int sy  = y0 - 4 + s;
        const int kdy = wid + (DD - 1) - s;
        if (kdy >= 0 && kdy < DD && sy >= 0 && sy < Hn) {
            const ushort* ms = mband + (((size_t)b * Hn + sy) * DD + kdy) * (size_t)(Wn * MW)
                               + mrow * MW + kgrp;
            #pragma unroll
            for (int t6 = 0; t6 < 6; ++t6) {
                const int kb = (t6 == 5) ? 72 : t6 * 16;
                uint4 bw = *reinterpret_cast<const uint4*>(ms + t6 * 16 * MW);
                bf16x8 bfr = *reinterpret_cast<bf16x8*>(&bw);
                #pragma unroll
                for (int ct = 0; ct < 2; ++ct) {
                    bf16x8 afr = *reinterpret_cast<const bf16x8*>(&A_sh[pb][ct * 16 + mrow][kb + kgrp]);
                    acc[ct][t6] = __builtin_amdgcn_mfma_f32_16x16x32_bf16(afr, bfr, acc[ct][t6], 0, 0, 0);
                }
            }
        }

        // write-late into the other buffer (read next step); single barrier per step
        if (doSt) {
            uint2* d = reinterpret_cast<uint2*>(&A_sh[pb ^ 1][srow][4 + sseg * 16]);
            d[0] = make_uint2(v0.x, v0.y); d[1] = make_uint2(v0.z, v0.w);
            d[2] = make_uint2(v1.x, v1.y); d[3] = make_uint2(v1.z, v1.w);
        }
        __syncthreads();
    }

    // epilogue: wave wid -> y = y0+wid; C/D layout col=lane&15 (x), row=(lane>>4)*4+r (c)
    const int y = y0 + wid;
    const int csub = kq << 2;
    #pragma unroll
    for (int ct = 0; ct < 2; ++ct)
        #pragma unroll
        for (int t6 = 0; t6 < 6; ++t6)
            #pragma unroll
            for (int r = 0; r < 4; ++r)
                out[(((size_t)b * Cn + c0 + ct * 16 + csub + r) * Hn + y) * Wn + t6 * 16 + mrow]
                    = acc[ct][t6][r];
}

// ---- fallback (ws too small): proven R8 fp32 scalar kernel ----
#define NTXf 12
#define NTCf 32
#define NTHf (NTXf*NTCf)
#define LWf  100
#define LW4f (LWf/4)
__global__ __launch_bounds__(NTHf, 6)
void corrT8_kernel(const float* __restrict__ corr, const float* __restrict__ feat,
                   float* __restrict__ out)
{
    __shared__ float lds[D2 * LWf];
    int bid = blockIdx.x;
    int sw  = (bid & 7) * (gridDim.x >> 3) + (bid >> 3);
    int cg  = sw & 3;
    int y   = (sw >> 2) % Hn;
    int b   = sw / (4 * Hn);
    const int tid = threadIdx.x;
    const float* corrb = corr + (size_t)b * D2 * HWn;
    for (int idx = tid; idx < D2 * LW4f; idx += NTHf) {
        int row = idx / LW4f, c4 = idx - row * LW4f;
        int kdy = row / DD, kdx = row - kdy * DD;
        int sy  = y + RR - kdy;
        float4 v = make_float4(0.f, 0.f, 0.f, 0.f);
        if (sy >= 0 && sy < Hn) {
            const float* src = corrb + (size_t)row * HWn + sy * Wn;
            #pragma unroll
            for (int e = 0; e < 4; ++e) {
                int sx = c4 * 4 + e - kdx;
                if (sx >= 0 && sx < Wn) (&v.x)[e] = src[sx];
            }
        }
        *reinterpret_cast<float4*>(&lds[row * LWf + c4 * 4]) = v;
    }
    __syncthreads();
    const int tx = tid % NTXf, tc = tid / NTXf;
    const int x0 = tx * 8, c0 = cg * 64 + tc * 2;
    const float* featp = feat + ((size_t)b * Cn + c0) * HWn;
    float acc[2][8] = {};
    const int klo = max(0, y - (Hn - 1 - RR)), khi = min(DD - 1, y + RR);
    #pragma unroll 1
    for (int kdy = klo; kdy <= khi; ++kdy) {
        int sy = y + RR - kdy;
        float f[2][16];
        const float* frow = featp + sy * Wn + x0 - RR;
        #pragma unroll
        for (int c = 0; c < 2; ++c) {
            const float* p = frow + (size_t)c * HWn;
            float4 f0 = (tx == 0) ? make_float4(0,0,0,0) : *reinterpret_cast<const float4*>(p);
            float4 f1 = *reinterpret_cast<const float4*>(p + 4);
            float4 f2 = *reinterpret_cast<const float4*>(p + 8);
            float4 f3 = (tx == NTXf-1) ? make_float4(0,0,0,0) : *reinterpret_cast<const float4*>(p + 12);
            f[c][0]=f0.x; f[c][1]=f0.y; f[c][2]=f0.z; f[c][3]=f0.w;
            f[c][4]=f1.x; f[c][5]=f1.y; f[c][6]=f1.z; f[c][7]=f1.w;
            f[c][8]=f2.x; f[c][9]=f2.y; f[c][10]=f2.z; f[c][11]=f2.w;
            f[c][12]=f3.x; f[c][13]=f3.y; f[c][14]=f3.z; f[c][15]=f3.w;
        }
        const float4* base = reinterpret_cast<const float4*>(lds) + (tx * 2 + 1) + kdy * DD * LW4f;
        float4 ca = base[0], cb = base[1];
        #pragma unroll
        for (int kdx = 0; kdx < DD; ++kdx) {
            float4 na = ca, nb = cb;
            if (kdx < DD - 1) { na = base[(kdx+1)*LW4f]; nb = base[(kdx+1)*LW4f + 1]; }
            float cv[8] = {ca.x, ca.y, ca.z, ca.w, cb.x, cb.y, cb.z, cb.w};
            #pragma unroll
            for (int c = 0; c < 2; ++c)
                #pragma unroll
                for (int j = 0; j < 8; ++j)
                    acc[c][j] = fmaf(cv[j], f[c][j + 8 - kdx], acc[c][j]);
            ca = na; cb = nb;
        }
    }
    float* ob = out + ((size_t)b * Cn + c0) * HWn + (size_t)y * Wn + x0;
    #pragma unroll
    for (int c = 0; c < 2; ++c) {
        *reinterpret_cast<float4*>(ob + (size_t)c * HWn)     = make_float4(acc[c][0], acc[c][1], acc[c][2], acc[c][3]);
        *reinterpret_cast<float4*>(ob + (size_t)c * HWn + 4) = make_float4(acc[c][4], acc[c][5], acc[c][6], acc[c][7]);
    }
}

extern "C" void kernel_launch(void* const* d_in, const int* in_sizes, int n_in,
                              void* d_out, int out_size, void* d_ws, size_t ws_size,
                              hipStream_t stream)
{
    const float* corr = (const float*)d_in[0];   // [16,81,96,96]
    const float* feat = (const float*)d_in[1];   // [16,256,96,96]
    float* out = (float*)d_out;                  // [16,256,96,96]

    const size_t needF = (size_t)Bn * Cn * HWn * 2;              // 75,497,472
    const size_t needM = (size_t)Bn * Hn * DD * Wn * MW * 2;     // 84,934,656

    if (ws_size >= needF + needM) {
        ushort* featb = (ushort*)d_ws;
        ushort* mband = (ushort*)((char*)d_ws + needF);
        prep_all_kernel<<<PREP_MB + PREP_FT, 384, 0, stream>>>(feat, corr, featb, mband);
        corrT19_kernel<<<Bn * Hn, 512, 0, stream>>>(featb, mband, out);
    } else {
        corrT8_kernel<<<Bn * Hn * 4, NTHf, 0, stream>>>(corr, feat, out);
    }
}